// Round 1
// baseline (185.561 us; speedup 1.0000x reference)
//
#include <hip/hip_runtime.h>

// DenseCRF-RNN fwd, D=64,H=128,W=128, L=2, 5 iters.
// Reduction: 2-label softmax == sigmoid of channel difference `delta`.
// Per iter: delta_new = P - A*blur3d(sigmoid(delta)) - B*bilat(sigmoid(delta))
// where P = dU - (Ksp*blurOnes + Kbl*bilatOnes) is precomputed once.
// A  = cd0*(sw01-sw00)+cd1*(sw11-sw10), B analogous with bw,
// Ksp= cd0*sw00+cd1*sw10, Kbl analogous; cd_m = compat[1,m]-compat[0,m].
// ws layout: dA[N] | dB[N] | P[N]  (12 MB).

#define DD 64
#define HH 128
#define WW 128
#define NN (DD*HH*WW)   // 1048576

__device__ __forceinline__ float bfac(int p, int dim) {
    // per-axis blur-of-ones factor (zero-padded 5-tap)
    const float K[5] = {0.05448868f, 0.24420134f, 0.40261995f, 0.24420134f, 0.05448868f};
    float s = 0.f;
#pragma unroll
    for (int o = -2; o <= 2; ++o) {
        int pp = p + o;
        s += (pp >= 0 && pp < dim) ? K[o + 2] : 0.f;
    }
    return s;
}

__global__ __launch_bounds__(256) void crf_pre(
    const float* __restrict__ img, const float* __restrict__ h,
    const float* __restrict__ f1, const float* __restrict__ w0,
    const float* __restrict__ sw, const float* __restrict__ bw,
    const float* __restrict__ cm,
    float* __restrict__ dA, float* __restrict__ P)
{
    const float Sc[4] = {1.f, 0.80073740f, 0.64118039f, 0.51341712f};
    int g = blockIdx.x * 256 + threadIdx.x;
    if (g >= NN) return;
    int z = g >> 14, rem = g & 16383, y = rem >> 7, x = rem & 127;

    float cd0 = cm[2] - cm[0], cd1 = cm[3] - cm[1];
    float Ksp = cd0 * sw[0] + cd1 * sw[2];
    float Kbl = cd0 * bw[0] + cd1 * bw[2];

    float Ic = img[g];
    float h0 = h[g], h1 = h[NN + g], fv = f1[g];
    float logp = -0.5f * Ic * Ic - 0.91893853320467274f;   // N(0,1) logpdf
    float t = -(w0[0] + logp - fv);

    float bones = bfac(z, DD) * bfac(y, HH) * bfac(x, WW);

    float den = 0.f, num = 0.f;
#pragma unroll
    for (int dz = -1; dz <= 1; ++dz)
#pragma unroll
        for (int dy = -1; dy <= 1; ++dy)
#pragma unroll
            for (int dx = -1; dx <= 1; ++dx) {
                int nz = z + dz, ny = y + dy, nx = x + dx;
                bool inb = (unsigned)nz < 64u && (unsigned)ny < 128u && (unsigned)nx < 128u;
                float In = inb ? img[g + dz * 16384 + dy * 128 + dx] : 0.f;
                float dd = Ic - In;
                float w = Sc[dz * dz + dy * dy + dx * dx] * __expf(-2.f * dd * dd);
                den += w;
                num += inb ? w : 0.f;
            }
    float Cf = Ksp * bones + Kbl * (num / den);
    dA[g] = h1 - h0;                 // initial delta = logits diff
    P[g]  = (h1 - h0) * t - Cf;      // dU - Cf
}

// Tile: 8(z) x 8(y) x 16(x) outputs per block, 256 threads, 4 x-voxels/thread.
template <bool LAST>
__global__ __launch_bounds__(256) void crf_iter(
    const float* __restrict__ dsrc, float* __restrict__ ddst,
    const float* __restrict__ img, const float* __restrict__ P,
    const float* __restrict__ sw, const float* __restrict__ bw,
    const float* __restrict__ cm,
    const float* __restrict__ f1, float* __restrict__ out)
{
    const float K0 = 0.05448868f, K1 = 0.24420134f, K2 = 0.40261995f;
    const float Sc[4] = {1.f, 0.80073740f, 0.64118039f, 0.51341712f};

    __shared__ float qs[12][12][20];   // sigmoid(delta), halo 2; x-idx = gx-x0+2
    __shared__ float ims[10][10][20];  // image, halo 1; x-idx = gx-x0+1 (18 used)
    __shared__ float t1[12][12][16];   // blur-x
    __shared__ float t2[12][8][16];    // blur-xy

    const int tid = threadIdx.x;
    const int x0 = blockIdx.x * 16, y0 = blockIdx.y * 8, zB = blockIdx.z * 8;

    const float cd0 = cm[2] - cm[0], cd1 = cm[3] - cm[1];
    const float Ac = cd0 * (sw[1] - sw[0]) + cd1 * (sw[3] - sw[2]);
    const float Bc = cd0 * (bw[1] - bw[0]) + cd1 * (bw[3] - bw[2]);

    float* qf = &qs[0][0][0];
    for (int idx = tid; idx < 2880; idx += 256) {
        int lz = idx / 240, r = idx - lz * 240, ly = r / 20, lx = r - ly * 20;
        int gz = zB + lz - 2, gy = y0 + ly - 2, gx = x0 + lx - 2;
        float v = 0.f;
        if ((unsigned)gz < 64u && (unsigned)gy < 128u && (unsigned)gx < 128u)
            v = 1.f / (1.f + __expf(-dsrc[(gz << 14) + (gy << 7) + gx]));
        qf[idx] = v;
    }
    float* imf = &ims[0][0][0];
    for (int idx = tid; idx < 2000; idx += 256) {
        int lz = idx / 200, r = idx - lz * 200, ly = r / 20, lx = r - ly * 20;
        int gz = zB + lz - 1, gy = y0 + ly - 1, gx = x0 + lx - 1;
        float v = 0.f;
        if ((unsigned)gz < 64u && (unsigned)gy < 128u && (unsigned)gx < 128u)
            v = img[(gz << 14) + (gy << 7) + gx];
        imf[idx] = v;
    }
    __syncthreads();

    // blur along x: t1[12][12][16]
    for (int idx = tid; idx < 576; idx += 256) {
        int lz = idx / 48, r = idx - lz * 48, ly = r / 4, c4 = (r - ly * 4) * 4;
        const float* row = &qs[lz][ly][c4];
        float4 a = *(const float4*)row;
        float4 b = *(const float4*)(row + 4);
        float4 o;
        o.x = K0 * (a.x + b.x) + K1 * (a.y + a.w) + K2 * a.z;
        o.y = K0 * (a.y + b.y) + K1 * (a.z + b.x) + K2 * a.w;
        o.z = K0 * (a.z + b.z) + K1 * (a.w + b.y) + K2 * b.x;
        o.w = K0 * (a.w + b.w) + K1 * (b.x + b.z) + K2 * b.y;
        *(float4*)&t1[lz][ly][c4] = o;
    }
    __syncthreads();

    // blur along y: t2[12][8][16]
    for (int idx = tid; idx < 384; idx += 256) {
        int lz = idx / 32, r = idx - lz * 32, ly = r / 4, c4 = (r - ly * 4) * 4;
        float4 r0 = *(const float4*)&t1[lz][ly][c4];
        float4 r1 = *(const float4*)&t1[lz][ly + 1][c4];
        float4 r2 = *(const float4*)&t1[lz][ly + 2][c4];
        float4 r3 = *(const float4*)&t1[lz][ly + 3][c4];
        float4 r4 = *(const float4*)&t1[lz][ly + 4][c4];
        float4 o;
        o.x = K0 * (r0.x + r4.x) + K1 * (r1.x + r3.x) + K2 * r2.x;
        o.y = K0 * (r0.y + r4.y) + K1 * (r1.y + r3.y) + K2 * r2.y;
        o.z = K0 * (r0.z + r4.z) + K1 * (r1.z + r3.z) + K2 * r2.z;
        o.w = K0 * (r0.w + r4.w) + K1 * (r1.w + r3.w) + K2 * r2.w;
        *(float4*)&t2[lz][ly][c4] = o;
    }
    __syncthreads();

    // final: each thread owns (lz, ly, x0+lx .. +3)
    const int lx = (tid & 3) * 4;
    const int ly = (tid >> 2) & 7;
    const int lz = tid >> 5;

    float4 za = *(const float4*)&t2[lz][ly][lx];
    float4 zb = *(const float4*)&t2[lz + 1][ly][lx];
    float4 zc = *(const float4*)&t2[lz + 2][ly][lx];
    float4 zd = *(const float4*)&t2[lz + 3][ly][lx];
    float4 ze = *(const float4*)&t2[lz + 4][ly][lx];
    float sp[4];
    sp[0] = K0 * (za.x + ze.x) + K1 * (zb.x + zd.x) + K2 * zc.x;
    sp[1] = K0 * (za.y + ze.y) + K1 * (zb.y + zd.y) + K2 * zc.y;
    sp[2] = K0 * (za.z + ze.z) + K1 * (zb.z + zd.z) + K2 * zc.z;
    sp[3] = K0 * (za.w + ze.w) + K1 * (zb.w + zd.w) + K2 * zc.w;

    float Ic[4];
    {
        float4 c0 = *(const float4*)&ims[lz + 1][ly + 1][lx];
        float4 c1 = *(const float4*)&ims[lz + 1][ly + 1][lx + 4];
        Ic[0] = c0.y; Ic[1] = c0.z; Ic[2] = c0.w; Ic[3] = c1.x;
    }
    float num[4] = {0, 0, 0, 0}, den[4] = {0, 0, 0, 0};
#pragma unroll
    for (int dz = -1; dz <= 1; ++dz) {
#pragma unroll
        for (int dy = -1; dy <= 1; ++dy) {
            float4 qa = *(const float4*)&qs[lz + 2 + dz][ly + 2 + dy][lx];
            float4 qb = *(const float4*)&qs[lz + 2 + dz][ly + 2 + dy][lx + 4];
            float4 ia = *(const float4*)&ims[lz + 1 + dz][ly + 1 + dy][lx];
            float4 ib = *(const float4*)&ims[lz + 1 + dz][ly + 1 + dy][lx + 4];
            float q8[8] = {qa.x, qa.y, qa.z, qa.w, qb.x, qb.y, qb.z, qb.w};
            float i8[8] = {ia.x, ia.y, ia.z, ia.w, ib.x, ib.y, ib.z, ib.w};
#pragma unroll
            for (int dx = -1; dx <= 1; ++dx) {
                const float s = Sc[dz * dz + dy * dy + dx * dx];
#pragma unroll
                for (int xi = 0; xi < 4; ++xi) {
                    float dd = Ic[xi] - i8[1 + xi + dx];
                    float w = s * __expf(-2.f * dd * dd);
                    den[xi] += w;
                    num[xi] += w * q8[2 + xi + dx];
                }
            }
        }
    }

    const int g = ((zB + lz) << 14) + ((y0 + ly) << 7) + (x0 + lx);
    float4 Pv = *(const float4*)&P[g];
    float pr[4] = {Pv.x, Pv.y, Pv.z, Pv.w};
    float dn[4];
#pragma unroll
    for (int xi = 0; xi < 4; ++xi)
        dn[xi] = pr[xi] - Ac * sp[xi] - Bc * (num[xi] / den[xi]);

    if (!LAST) {
        float4 o = {dn[0], dn[1], dn[2], dn[3]};
        *(float4*)&ddst[g] = o;
    } else {
        float q1[4];
#pragma unroll
        for (int xi = 0; xi < 4; ++xi) q1[xi] = 1.f / (1.f + __expf(-dn[xi]));
        float4 o1 = {q1[0], q1[1], q1[2], q1[3]};
        float4 o0 = {1.f - q1[0], 1.f - q1[1], 1.f - q1[2], 1.f - q1[3]};
        *(float4*)&out[g] = o0;
        *(float4*)&out[NN + g] = o1;
        float4 fv = *(const float4*)&f1[g];
        *(float4*)&out[2 * NN + g] = fv;
    }
}

extern "C" void kernel_launch(void* const* d_in, const int* in_sizes, int n_in,
                              void* d_out, int out_size, void* d_ws, size_t ws_size,
                              hipStream_t stream)
{
    const float* img = (const float*)d_in[0];
    const float* h   = (const float*)d_in[1];
    const float* f1  = (const float*)d_in[2];
    const float* w0  = (const float*)d_in[3];
    const float* sw  = (const float*)d_in[4];
    const float* bw  = (const float*)d_in[5];
    const float* cm  = (const float*)d_in[6];
    float* out = (float*)d_out;

    float* dA = (float*)d_ws;
    float* dB = dA + NN;
    float* P  = dB + NN;

    crf_pre<<<NN / 256, 256, 0, stream>>>(img, h, f1, w0, sw, bw, cm, dA, P);

    dim3 grid(WW / 16, HH / 8, DD / 8);   // (8,16,8) = 1024 blocks
    crf_iter<false><<<grid, 256, 0, stream>>>(dA, dB, img, P, sw, bw, cm, nullptr, nullptr);
    crf_iter<false><<<grid, 256, 0, stream>>>(dB, dA, img, P, sw, bw, cm, nullptr, nullptr);
    crf_iter<false><<<grid, 256, 0, stream>>>(dA, dB, img, P, sw, bw, cm, nullptr, nullptr);
    crf_iter<false><<<grid, 256, 0, stream>>>(dB, dA, img, P, sw, bw, cm, nullptr, nullptr);
    crf_iter<true ><<<grid, 256, 0, stream>>>(dA, nullptr, img, P, sw, bw, cm, f1, out);
}